// Round 2
// baseline (81445.282 us; speedup 1.0000x reference)
//
#include <hip/hip_runtime.h>
#include <math.h>

// Problem sizes (fixed by reference)
#define TT 2048
#define BB 64
#define IIN 128
#define HHID 512
#define OOUT 64
#define OUT_OFF (BB * HHID)   // h_final [B,H] then outs [B,T,O]

// Decomposition: 16 groups x 16 WGs. Group g owns batches 4g..4g+3.
// WG w owns h-rows [32w, 32w+32) and Who rows [4w, 4w+4).
// 256 threads = 4 waves; wave wv owns 8 h-rows (32w+8wv..+7) + Who row 4w+wv.
// Lane l owns k-chunk [8l, 8l+8). No intra-WG sync in the main loop.
#define NGRP 16
#define NTHR 256

// LDS layout (float offsets). W rows 0..31 = Whh slice, 32..35 = Who rows.
#define LDS_W 0                         // [36][512] swizzled
#define LDS_WIH (LDS_W + 36 * 512)      // [32][128] linear
#define LDS_TOTAL (LDS_WIH + 32 * 128)  // 22528 floats = 90112 B

__device__ __forceinline__ int swzW(int k) {
  // XOR quad-index with k-bits[5:7]: spreads the 4 lane-classes (8l mod 32)
  // across all 8 quads; lanes l and l+32 share a bank (2-way = free).
  return k ^ (4 * ((k >> 5) & 7));
}

extern "C" __global__ void __launch_bounds__(NTHR, 1)
rnn_kernel(const float* __restrict__ inputs,
           const float* __restrict__ hidden,
           const float* __restrict__ in_noise,
           const float* __restrict__ re_noise,
           const float* __restrict__ Wih,
           const float* __restrict__ Whh,
           const float* __restrict__ bhh,
           const float* __restrict__ Who,
           const float* __restrict__ bho,
           float* __restrict__ out,
           unsigned int* __restrict__ flags,  // [16][64] per-wave epochs
           float* __restrict__ th_buf)        // [2][16][4][512] f32
{
  extern __shared__ float smem[];
  const int tid = threadIdx.x;
  const int l  = tid & 63;
  const int wv = tid >> 6;               // wave 0..3
  const int g = blockIdx.x & 15;         // group
  const int w = blockIdx.x >> 4;         // member 0..15
  const int j0 = w * 32;

  // ---------------- stage weights into LDS (once) ----------------
  for (int c = tid; c < 32 * 128; c += NTHR) {        // Whh rows 0..31
    int j = c >> 7, k4 = (c & 127) << 2;
    float4 v = *(const float4*)&Whh[(long)(j0 + j) * HHID + k4];
    *(float4*)&smem[LDS_W + j * 512 + swzW(k4)] = v;
  }
  for (int c = tid; c < 4 * 128; c += NTHR) {         // Who rows 32..35
    int j = c >> 7, k4 = (c & 127) << 2;
    float4 v = *(const float4*)&Who[(long)(4 * w + j) * HHID + k4];
    *(float4*)&smem[LDS_W + (32 + j) * 512 + swzW(k4)] = v;
  }
  for (int c = tid; c < 32 * 32; c += NTHR) {         // Wih rows 0..31
    int j = c >> 5, i4 = (c & 31) << 2;
    float4 v = *(const float4*)&Wih[(long)(j0 + j) * IIN + i4];
    *(float4*)&smem[LDS_WIH + j * 128 + i4] = v;
  }
  __syncthreads();   // weights ready (only barrier besides none in loop)

  // ---------------- per-lane constants ----------------
  const bool redlane = (l & 1) == 0;     // holds reduced h output v = l>>1
  const int v  = (l >> 1) & 31;
  const int rr = v >> 2;                 // local h row 0..7
  const int bb = v & 3;                  // batch
  const int grow = j0 + 8 * wv + rr;     // global h row
  const int ob = (l >> 4) & 3;           // out batch (Who reduce layout)
  const bool outlane = (l & 15) == 0;
  const int oc = 4 * w + wv;             // global Who row
  const int k0 = 8 * l;
  const int kx = k0 ^ (4 * ((l >> 2) & 7));   // swizzled W read addr (quad 0)

  float bhh_v = 0.f, hreg = 0.f;
  if (redlane) {
    bhh_v = bhh[grow];
    hreg = hidden[(long)(4 * g + bb) * HHID + grow];
    __hip_atomic_store(&th_buf[((0 * NGRP + g) * 4 + bb) * HHID + grow],
                       tanhf(hreg), __ATOMIC_RELAXED, __HIP_MEMORY_SCOPE_AGENT);
  }
  const float bho_v = bho[oc];
  if (l == 0)
    __hip_atomic_store(&flags[g * 64 + w * 4 + wv], 1u,
                       __ATOMIC_RELEASE, __HIP_MEMORY_SCOPE_AGENT);

  for (int t = 0; t <= TT; ++t) {
    // ---- issue x / noise loads for step t (hide under the spin) ----
    float2 xi[4], xn[4];
    float nre = 0.f;
    if (t < TT) {
      #pragma unroll
      for (int b = 0; b < 4; ++b) {
        long off = ((long)(4 * g + b) * TT + t) * IIN + 2 * l;
        xi[b] = *(const float2*)&inputs[off];
        xn[b] = *(const float2*)&in_noise[off];
      }
      if (redlane)
        nre = re_noise[((long)(4 * g + bb) * TT + t) * HHID + grow];
    }

    // ---- spin: all 64 producer waves of this group at epoch >= t+1 ----
    {
      const unsigned tgt = (unsigned)(t + 1);
      unsigned f = __hip_atomic_load(&flags[g * 64 + l], __ATOMIC_RELAXED,
                                     __HIP_MEMORY_SCOPE_AGENT);
      while (!__all((int)(f >= tgt)))
        f = __hip_atomic_load(&flags[g * 64 + l], __ATOMIC_RELAXED,
                              __HIP_MEMORY_SCOPE_AGENT);
    }
    __builtin_amdgcn_fence(__ATOMIC_ACQUIRE, "agent");

    // ---- th(t) loads: straight to registers from MALL ----
    const float* thsrc = th_buf + ((long)(t & 1) * NGRP + g) * 4 * HHID;
    float4 tha[4], thb[4];
    #pragma unroll
    for (int b = 0; b < 4; ++b) {
      tha[b] = *(const float4*)&thsrc[b * HHID + k0];
      thb[b] = *(const float4*)&thsrc[b * HHID + k0 + 4];
    }

    float accH[32];
    float accO[4];
    #pragma unroll
    for (int i = 0; i < 32; ++i) accH[i] = 0.f;

    // ---- Wih @ x (overlaps th latency) ----
    if (t < TT) {
      float xv[4][2];
      #pragma unroll
      for (int b = 0; b < 4; ++b) {
        xv[b][0] = xi[b].x * (1.f + 0.01f * xn[b].x);
        xv[b][1] = xi[b].y * (1.f + 0.01f * xn[b].y);
      }
      #pragma unroll
      for (int r = 0; r < 8; ++r) {
        float2 wih = *(const float2*)&smem[LDS_WIH + (8 * wv + r) * 128 + 2 * l];
        #pragma unroll
        for (int b = 0; b < 4; ++b)
          accH[r * 4 + b] += wih.x * xv[b][0] + wih.y * xv[b][1];
      }
    }

    // ---- Whh @ th : 8 h-rows ----
    if (t < TT) {
      #pragma unroll
      for (int r = 0; r < 8; ++r) {
        int base = LDS_W + (8 * wv + r) * 512;
        float4 w0 = *(const float4*)&smem[base + kx];
        float4 w1 = *(const float4*)&smem[base + (kx ^ 4)];
        #pragma unroll
        for (int b = 0; b < 4; ++b) {
          accH[r * 4 + b] += w0.x * tha[b].x + w0.y * tha[b].y +
                             w0.z * tha[b].z + w0.w * tha[b].w +
                             w1.x * thb[b].x + w1.y * thb[b].y +
                             w1.z * thb[b].z + w1.w * thb[b].w;
        }
      }
    }
    // ---- Who row (always) ----
    {
      int base = LDS_W + (32 + wv) * 512;
      float4 w0 = *(const float4*)&smem[base + kx];
      float4 w1 = *(const float4*)&smem[base + (kx ^ 4)];
      #pragma unroll
      for (int b = 0; b < 4; ++b) {
        accO[b] = w0.x * tha[b].x + w0.y * tha[b].y +
                  w0.z * tha[b].z + w0.w * tha[b].w +
                  w1.x * thb[b].x + w1.y * thb[b].y +
                  w1.z * thb[b].z + w1.w * thb[b].w;
      }
    }

    // ---- butterfly reduce accH: 64 lanes x 32 vals -> lane l holds v=l>>1 ----
    if (t < TT) {
      #pragma unroll
      for (int rd = 0; rd < 5; ++rd) {
        const int m = 32 >> rd;
        const int half = 16 >> rd;
        const bool hi = (l & m) != 0;
        #pragma unroll
        for (int j = 0; j < half; ++j) {
          float send = hi ? accH[j] : accH[j + half];
          float recv = __shfl_xor(send, m, 64);
          accH[j] = (hi ? accH[j + half] : accH[j]) + recv;
        }
      }
      accH[0] += __shfl_xor(accH[0], 1, 64);
    }
    // ---- reduce accO: -> lanes with b = (l>>4)&3 ----
    {
      {
        const bool hi = (l & 32) != 0;
        float s0 = hi ? accO[0] : accO[2];
        float s1 = hi ? accO[1] : accO[3];
        float r0 = __shfl_xor(s0, 32, 64);
        float r1 = __shfl_xor(s1, 32, 64);
        accO[0] = (hi ? accO[2] : accO[0]) + r0;
        accO[1] = (hi ? accO[3] : accO[1]) + r1;
      }
      {
        const bool hi = (l & 16) != 0;
        float s0 = hi ? accO[0] : accO[1];
        float r0 = __shfl_xor(s0, 16, 64);
        accO[0] = (hi ? accO[1] : accO[0]) + r0;
      }
      accO[0] += __shfl_xor(accO[0], 8, 64);
      accO[0] += __shfl_xor(accO[0], 4, 64);
      accO[0] += __shfl_xor(accO[0], 2, 64);
      accO[0] += __shfl_xor(accO[0], 1, 64);
    }

    // ---- h update + publish th(t+1) ----
    if (t < TT && redlane) {
      float dh = -hreg + accH[0] + bhh_v + 0.01f * nre;
      hreg += 0.1f * dh;   // ALPHA = DT/TAU
      __hip_atomic_store(
          &th_buf[((((t + 1) & 1) * NGRP + g) * 4 + bb) * HHID + grow],
          tanhf(hreg), __ATOMIC_RELAXED, __HIP_MEMORY_SCOPE_AGENT);
    }
    // ---- out(t-1) store ----
    if (t > 0 && outlane) {
      long oof = (long)OUT_OFF + ((long)(4 * g + ob) * TT + (t - 1)) * OOUT + oc;
      out[oof] = accO[0] + bho_v;
    }
    // ---- advance epoch (release orders the th stores above) ----
    if (t < TT && l == 0)
      __hip_atomic_store(&flags[g * 64 + w * 4 + wv], (unsigned)(t + 2),
                         __ATOMIC_RELEASE, __HIP_MEMORY_SCOPE_AGENT);
  }

  // ---- final hidden state ----
  if (redlane)
    out[(long)(4 * g + bb) * HHID + grow] = hreg;
}

extern "C" void kernel_launch(void* const* d_in, const int* in_sizes, int n_in,
                              void* d_out, int out_size, void* d_ws, size_t ws_size,
                              hipStream_t stream) {
  const float* inputs  = (const float*)d_in[0];
  const float* hidden  = (const float*)d_in[1];
  const float* innoise = (const float*)d_in[2];
  const float* renoise = (const float*)d_in[3];
  const float* Wih     = (const float*)d_in[4];
  const float* Whh     = (const float*)d_in[5];
  const float* bhh     = (const float*)d_in[6];
  const float* Who     = (const float*)d_in[7];
  const float* bho     = (const float*)d_in[8];
  float* out = (float*)d_out;

  unsigned int* flags = (unsigned int*)d_ws;            // [16][64] u32 = 4KB
  float* th_buf = (float*)((char*)d_ws + 4096);         // [2][16][4][512] f32

  hipMemsetAsync(d_ws, 0, 4096, stream);                // reset epochs

  int lds_bytes = LDS_TOTAL * 4;
  hipFuncSetAttribute(reinterpret_cast<const void*>(rnn_kernel),
                      hipFuncAttributeMaxDynamicSharedMemorySize, lds_bytes);
  hipLaunchKernelGGL(rnn_kernel, dim3(256), dim3(NTHR), lds_bytes, stream,
                     inputs, hidden, innoise, renoise, Wih, Whh, bhh, Who, bho,
                     out, flags, th_buf);
}

// Round 3
// 61218.231 us; speedup vs baseline: 1.3304x; 1.3304x over previous
//
#include <hip/hip_runtime.h>
#include <math.h>

// Problem sizes (fixed by reference)
#define TT 2048
#define BB 64
#define IIN 128
#define HHID 512
#define OOUT 64
#define OUT_OFF (BB * HHID)   // h_final [B,H] then outs [B,T,O]

// Decomposition: 16 groups x 16 WGs. Group g owns batches 4g..4g+3.
// WG w owns h-rows [32w,32w+32) and Who rows [4w,4w+4).
// 256 threads = 4 waves; wave wv owns 8 h-rows + Who row 4w+wv.
// Lane l owns k-chunk [8l,8l+8). ALL weights live in VGPRs; no LDS at all.
// Sync: per-group epoch counter, relaxed atomics only (no fences/release —
// R2 showed per-step buffer_inv/buffer_wbl2 is an 8x disaster).
#define NGRP 16
#define NTHR 256

extern "C" __global__ void __launch_bounds__(NTHR, 2)   // cap VGPR<=256: any 2 WGs co-fit per CU -> no residency deadlock
rnn_kernel(const float* __restrict__ inputs,
           const float* __restrict__ hidden,
           const float* __restrict__ in_noise,
           const float* __restrict__ re_noise,
           const float* __restrict__ Wih,
           const float* __restrict__ Whh,
           const float* __restrict__ bhh,
           const float* __restrict__ Who,
           const float* __restrict__ bho,
           float* __restrict__ out,
           unsigned int* __restrict__ cnt,    // [16] epoch counters, 64-dword stride
           float* __restrict__ th_buf)        // [2][16][4][512] f32
{
  const int tid = threadIdx.x;
  const int l  = tid & 63;
  const int wv = tid >> 6;               // wave 0..3
  const int g = blockIdx.x & 15;         // group (members bid%16==g -> same XCD under round-robin; perf only)
  const int w = blockIdx.x >> 4;         // member 0..15
  const int j0 = w * 32;
  const int k0 = 8 * l;                  // k-chunk base

  // ---------------- load weights into registers ----------------
  float4 whh[8][2];
  float2 wih[8];
  #pragma unroll
  for (int r = 0; r < 8; ++r) {
    const float* wr = &Whh[(long)(j0 + 8 * wv + r) * HHID + k0];
    whh[r][0] = *(const float4*)wr;
    whh[r][1] = *(const float4*)(wr + 4);
    wih[r] = *(const float2*)&Wih[(long)(j0 + 8 * wv + r) * IIN + 2 * l];
  }
  const int oc = 4 * w + wv;             // global Who row
  float4 who0 = *(const float4*)&Who[(long)oc * HHID + k0];
  float4 who1 = *(const float4*)&Who[(long)oc * HHID + k0 + 4];
  const float bho_v = bho[oc];

  // ---------------- per-lane reduce-output mapping ----------------
  const bool redlane = (l & 1) == 0;     // holds reduced h value v = l>>1
  const int v  = (l >> 1) & 31;
  const int rr = v >> 2;                 // local h row 0..7
  const int bb = v & 3;                  // batch
  const int grow = j0 + 8 * wv + rr;     // global h row
  const int ob = (l >> 4) & 3;           // out batch
  const bool outlane = (l & 15) == 0;

  float bhh_v = 0.f, hreg = 0.f;
  if (redlane) {
    bhh_v = bhh[grow];
    hreg = hidden[(long)(4 * g + bb) * HHID + grow];
    __hip_atomic_store(&th_buf[((0 * NGRP + g) * 4 + bb) * HHID + grow],
                       tanhf(hreg), __ATOMIC_RELAXED, __HIP_MEMORY_SCOPE_AGENT);
  }
  asm volatile("s_waitcnt vmcnt(0)" ::: "memory");   // th(0) stores complete at L3
  if (l == 0)
    __hip_atomic_fetch_add(&cnt[g * 64], 1u, __ATOMIC_RELAXED,
                           __HIP_MEMORY_SCOPE_AGENT);

  for (int t = 0; t <= TT; ++t) {
    // ---- prefetch x / noise for step t (hidden under the spin) ----
    float2 xi[4], xn[4];
    float nre = 0.f;
    if (t < TT) {
      #pragma unroll
      for (int b = 0; b < 4; ++b) {
        long off = ((long)(4 * g + b) * TT + t) * IIN + 2 * l;
        xi[b] = *(const float2*)&inputs[off];
        xn[b] = *(const float2*)&in_noise[off];
      }
      if (redlane)
        nre = re_noise[((long)(4 * g + bb) * TT + t) * HHID + grow];
    }

    // ---- spin: all 64 waves of group at epoch >= t+1 (uniform 1-dword poll) ----
    {
      const unsigned tgt = 64u * (unsigned)(t + 1);
      unsigned f = __hip_atomic_load(&cnt[g * 64], __ATOMIC_RELAXED,
                                     __HIP_MEMORY_SCOPE_AGENT);
      while (f < tgt)
        f = __hip_atomic_load(&cnt[g * 64], __ATOMIC_RELAXED,
                              __HIP_MEMORY_SCOPE_AGENT);
    }
    asm volatile("" ::: "memory");   // don't hoist th loads above the spin

    // ---- th(t): relaxed-atomic loads straight into registers ----
    const float* thsrc = th_buf + ((long)(t & 1) * NGRP + g) * 4 * HHID;
    float th[4][8];
    #pragma unroll
    for (int b = 0; b < 4; ++b)
      #pragma unroll
      for (int j = 0; j < 8; ++j)
        th[b][j] = __hip_atomic_load(&thsrc[b * HHID + k0 + j],
                                     __ATOMIC_RELAXED, __HIP_MEMORY_SCOPE_AGENT);

    float accH[32], accO[4];

    // ---- Wih @ x (no th dependency: overlaps th load latency) ----
    if (t < TT) {
      float xv[4][2];
      #pragma unroll
      for (int b = 0; b < 4; ++b) {
        xv[b][0] = xi[b].x * (1.f + 0.01f * xn[b].x);
        xv[b][1] = xi[b].y * (1.f + 0.01f * xn[b].y);
      }
      #pragma unroll
      for (int r = 0; r < 8; ++r)
        #pragma unroll
        for (int b = 0; b < 4; ++b)
          accH[r * 4 + b] = wih[r].x * xv[b][0] + wih[r].y * xv[b][1];
    } else {
      #pragma unroll
      for (int i = 0; i < 32; ++i) accH[i] = 0.f;
    }

    // ---- Whh @ th : 8 rows x 4 batches x 8 k ----
    if (t < TT) {
      #pragma unroll
      for (int r = 0; r < 8; ++r)
        #pragma unroll
        for (int b = 0; b < 4; ++b) {
          accH[r * 4 + b] += whh[r][0].x * th[b][0] + whh[r][0].y * th[b][1] +
                             whh[r][0].z * th[b][2] + whh[r][0].w * th[b][3] +
                             whh[r][1].x * th[b][4] + whh[r][1].y * th[b][5] +
                             whh[r][1].z * th[b][6] + whh[r][1].w * th[b][7];
        }
    }
    // ---- Who row ----
    #pragma unroll
    for (int b = 0; b < 4; ++b)
      accO[b] = who0.x * th[b][0] + who0.y * th[b][1] +
                who0.z * th[b][2] + who0.w * th[b][3] +
                who1.x * th[b][4] + who1.y * th[b][5] +
                who1.z * th[b][6] + who1.w * th[b][7];

    // ---- butterfly reduce accH: lane l ends with value v=l>>1 in accH[0] ----
    if (t < TT) {
      #pragma unroll
      for (int rd = 0; rd < 5; ++rd) {
        const int m = 32 >> rd;
        const int half = 16 >> rd;
        const bool hi = (l & m) != 0;
        #pragma unroll
        for (int j = 0; j < half; ++j) {
          float send = hi ? accH[j] : accH[j + half];
          float recv = __shfl_xor(send, m, 64);
          accH[j] = (hi ? accH[j + half] : accH[j]) + recv;
        }
      }
      accH[0] += __shfl_xor(accH[0], 1, 64);
    }
    // ---- reduce accO -> lanes l&15==0, batch (l>>4)&3 ----
    {
      {
        const bool hi = (l & 32) != 0;
        float s0 = hi ? accO[0] : accO[2];
        float s1 = hi ? accO[1] : accO[3];
        float r0 = __shfl_xor(s0, 32, 64);
        float r1 = __shfl_xor(s1, 32, 64);
        accO[0] = (hi ? accO[2] : accO[0]) + r0;
        accO[1] = (hi ? accO[3] : accO[1]) + r1;
      }
      {
        const bool hi = (l & 16) != 0;
        float s0 = hi ? accO[0] : accO[1];
        float r0 = __shfl_xor(s0, 16, 64);
        accO[0] = (hi ? accO[1] : accO[0]) + r0;
      }
      accO[0] += __shfl_xor(accO[0], 8, 64);
      accO[0] += __shfl_xor(accO[0], 4, 64);
      accO[0] += __shfl_xor(accO[0], 2, 64);
      accO[0] += __shfl_xor(accO[0], 1, 64);
    }

    // ---- h update + publish th(t+1) ----
    if (t < TT && redlane) {
      float dh = -hreg + accH[0] + bhh_v + 0.01f * nre;
      hreg += 0.1f * dh;   // ALPHA = DT/TAU
      __hip_atomic_store(
          &th_buf[((((t + 1) & 1) * NGRP + g) * 4 + bb) * HHID + grow],
          tanhf(hreg), __ATOMIC_RELAXED, __HIP_MEMORY_SCOPE_AGENT);
    }
    // ---- out(t-1) ----
    if (t > 0 && outlane) {
      long oof = (long)OUT_OFF + ((long)(4 * g + ob) * TT + (t - 1)) * OOUT + oc;
      out[oof] = accO[0] + bho_v;
    }
    // ---- drain own stores, then advance epoch (relaxed, fire-and-forget) ----
    if (t < TT) {
      asm volatile("s_waitcnt vmcnt(0)" ::: "memory");
      if (l == 0)
        __hip_atomic_fetch_add(&cnt[g * 64], 1u, __ATOMIC_RELAXED,
                               __HIP_MEMORY_SCOPE_AGENT);
    }
  }

  // ---- final hidden state ----
  if (redlane)
    out[(long)(4 * g + bb) * HHID + grow] = hreg;
}

extern "C" void kernel_launch(void* const* d_in, const int* in_sizes, int n_in,
                              void* d_out, int out_size, void* d_ws, size_t ws_size,
                              hipStream_t stream) {
  const float* inputs  = (const float*)d_in[0];
  const float* hidden  = (const float*)d_in[1];
  const float* innoise = (const float*)d_in[2];
  const float* renoise = (const float*)d_in[3];
  const float* Wih     = (const float*)d_in[4];
  const float* Whh     = (const float*)d_in[5];
  const float* bhh     = (const float*)d_in[6];
  const float* Who     = (const float*)d_in[7];
  const float* bho     = (const float*)d_in[8];
  float* out = (float*)d_out;

  unsigned int* cnt = (unsigned int*)d_ws;              // [16] epochs, 256B stride
  float* th_buf = (float*)((char*)d_ws + 4096);         // [2][16][4][512] f32

  hipMemsetAsync(d_ws, 0, 4096, stream);                // reset epochs

  hipLaunchKernelGGL(rnn_kernel, dim3(256), dim3(NTHR), 0, stream,
                     inputs, hidden, innoise, renoise, Wih, Whh, bhh, Who, bho,
                     out, cnt, th_buf);
}

// Round 4
// 32653.549 us; speedup vs baseline: 2.4942x; 1.8748x over previous
//
#include <hip/hip_runtime.h>
#include <math.h>

// Problem sizes (fixed by reference)
#define TT 2048
#define IIN 128
#define HHID 512
#define OOUT 64
#define OUT_OFF (64 * HHID)   // h_final [B,H] then outs [B,T,O]

// 16 groups x 16 WGs. Group g owns batches 4g..4g+3. WG w owns h-rows
// [32w,32w+32) + Who rows [4w,4w+4). 4 waves/WG; wave wv owns 8 h-rows +
// Who row 4w+wv; lane l owns k-chunk [8l,8l+8). Weights in VGPRs.
// th exchange: producers store scalar relaxed-agent atomics; consumers stage
// 8KB/WG/step via coalesced dwordx4 sc0sc1 loads -> swizzled LDS -> b128 reads.
// Sync: per-group epoch counter; 1 add per WG per step (LDS arrive);
// relaxed atomics only + explicit vmcnt drains (no fences: R2 lesson).
#define NTHR 256

typedef float f32x4 __attribute__((ext_vector_type(4)));

__device__ __forceinline__ void load2_bypass(const float* p0, const float* p1,
                                             f32x4& a, f32x4& b) {
  asm volatile("global_load_dwordx4 %0, %2, off sc0 sc1\n\t"
               "global_load_dwordx4 %1, %3, off sc0 sc1"
               : "=v"(a), "=v"(b) : "v"(p0), "v"(p1) : "memory");
}

// float-index swizzle: XOR chunk bits[2:4] with row bits (row = f>>5)
__device__ __forceinline__ int swzF(int f) {
  return f ^ (((f >> 5) & 7) << 2);
}

extern "C" __global__ void __launch_bounds__(NTHR, 1)
rnn_kernel(const float* __restrict__ inputs,
           const float* __restrict__ hidden,
           const float* __restrict__ in_noise,
           const float* __restrict__ re_noise,
           const float* __restrict__ Wih,
           const float* __restrict__ Whh,
           const float* __restrict__ bhh,
           const float* __restrict__ Who,
           const float* __restrict__ bho,
           float* __restrict__ out,
           unsigned int* __restrict__ cnt,    // [16] epoch counters, 64-dword stride
           float* __restrict__ th_buf)        // [2][16][4][512] f32
{
  __shared__ float lds_th[2][2048];   // double-buffered swizzled th tile
  __shared__ unsigned s_arrive;

  const int tid = threadIdx.x;
  const int l  = tid & 63;
  const int wv = tid >> 6;               // wave 0..3
  const int g = blockIdx.x & 15;         // group (bid%16 -> XCD affinity, perf only)
  const int w = blockIdx.x >> 4;         // member 0..15
  const int j0 = w * 32;
  const int k0 = 8 * l;

  // ---------------- weights into registers (cached loads, once) ----------------
  f32x4 whh[8][2];
  float2 wih[8];
  #pragma unroll
  for (int r = 0; r < 8; ++r) {
    const float* wr = &Whh[(long)(j0 + 8 * wv + r) * HHID + k0];
    whh[r][0] = *(const f32x4*)wr;
    whh[r][1] = *(const f32x4*)(wr + 4);
    wih[r] = *(const float2*)&Wih[(long)(j0 + 8 * wv + r) * IIN + 2 * l];
  }
  const int oc = 4 * w + wv;
  f32x4 who0 = *(const f32x4*)&Who[(long)oc * HHID + k0];
  f32x4 who1 = *(const f32x4*)&Who[(long)oc * HHID + k0 + 4];
  const float bho_v = bho[oc];

  // ---------------- reduce-output lane mapping ----------------
  const bool redlane = (l & 1) == 0;
  const int v  = (l >> 1) & 31;
  const int rr = v >> 2;                 // local h row 0..7
  const int bb = v & 3;                  // batch
  const int grow = j0 + 8 * wv + rr;
  const int ob = (l >> 4) & 3;
  const bool outlane = (l & 15) == 0;

  if (tid == 0) s_arrive = 0;

  float bhh_v = 0.f, hreg = 0.f;
  if (redlane) {
    bhh_v = bhh[grow];
    hreg = hidden[(long)(4 * g + bb) * HHID + grow];
    __hip_atomic_store(&th_buf[((0 * 16 + g) * 4 + bb) * HHID + grow],
                       tanhf(hreg), __ATOMIC_RELAXED, __HIP_MEMORY_SCOPE_AGENT);
  }
  __syncthreads();                       // drains vmcnt; s_arrive visible
  if (tid == 0)
    __hip_atomic_fetch_add(&cnt[g * 64], 1u, __ATOMIC_RELAXED,
                           __HIP_MEMORY_SCOPE_AGENT);

  // staging indices: thread tid stages chunks f0=4*tid, f1=1024+4*tid
  const int stg0 = swzF(4 * tid);                  // same XOR for both halves
  // read indices: lane l, batch b -> chunk f = 512b + 8l, swizzled
  const int rsw = ((l >> 2) & 7) << 2;             // XOR term (b part is 0 mod 8)

  for (int t = 0; t <= TT; ++t) {
    // ---- prefetch x / noise (cached loads; consumed before th wait) ----
    float2 xi[4], xn[4];
    float nre = 0.f;
    if (t < TT) {
      #pragma unroll
      for (int b = 0; b < 4; ++b) {
        long off = ((long)(4 * g + b) * TT + t) * IIN + 2 * l;
        xi[b] = *(const float2*)&inputs[off];
        xn[b] = *(const float2*)&in_noise[off];
      }
      if (redlane)
        nre = re_noise[((long)(4 * g + bb) * TT + t) * HHID + grow];
    }

    // ---- spin: group epoch >= t+1 (uniform poll, sleep-throttled) ----
    {
      const unsigned tgt = 16u * (unsigned)(t + 1);
      unsigned f = __hip_atomic_load(&cnt[g * 64], __ATOMIC_RELAXED,
                                     __HIP_MEMORY_SCOPE_AGENT);
      while (f < tgt) {
        __builtin_amdgcn_s_sleep(1);
        f = __hip_atomic_load(&cnt[g * 64], __ATOMIC_RELAXED,
                              __HIP_MEMORY_SCOPE_AGENT);
      }
    }

    // ---- stage th(t): coalesced bypass loads -> swizzled LDS ----
    const float* thsrc = th_buf + ((long)(t & 1) * 16 + g) * 4 * HHID;
    f32x4 c0, c1;
    load2_bypass(thsrc + 4 * tid, thsrc + 1024 + 4 * tid, c0, c1);

    float accH[32];
    // ---- Wih @ x (overlaps th load latency) ----
    if (t < TT) {
      float xv[4][2];
      #pragma unroll
      for (int b = 0; b < 4; ++b) {
        xv[b][0] = xi[b].x * (1.f + 0.01f * xn[b].x);
        xv[b][1] = xi[b].y * (1.f + 0.01f * xn[b].y);
      }
      #pragma unroll
      for (int r = 0; r < 8; ++r)
        #pragma unroll
        for (int b = 0; b < 4; ++b)
          accH[r * 4 + b] = wih[r].x * xv[b][0] + wih[r].y * xv[b][1];
    } else {
      #pragma unroll
      for (int i = 0; i < 32; ++i) accH[i] = 0.f;
    }

    asm volatile("s_waitcnt vmcnt(0)" : "+v"(c0), "+v"(c1) :: "memory");
    float* dst = lds_th[t & 1];
    *(f32x4*)&dst[stg0] = c0;
    *(f32x4*)&dst[2048 - 2048 + 1024 + (stg0 ^ (swzF(4 * tid + 1024) ^ (stg0 + 1024)))] = c1; // = swzF(1024+4tid)
    __syncthreads();

    // ---- read th from LDS (8-way b128 floor) ----
    const float* src = lds_th[t & 1];
    f32x4 tha[4], thb[4];
    #pragma unroll
    for (int b = 0; b < 4; ++b) {
      int f0 = (512 * b + 8 * l) ^ rsw;
      tha[b] = *(const f32x4*)&src[f0];
      thb[b] = *(const f32x4*)&src[f0 ^ 4];
    }

    // ---- Whh @ th ----
    if (t < TT) {
      #pragma unroll
      for (int r = 0; r < 8; ++r)
        #pragma unroll
        for (int b = 0; b < 4; ++b)
          accH[r * 4 + b] += whh[r][0].x * tha[b].x + whh[r][0].y * tha[b].y +
                             whh[r][0].z * tha[b].z + whh[r][0].w * tha[b].w +
                             whh[r][1].x * thb[b].x + whh[r][1].y * thb[b].y +
                             whh[r][1].z * thb[b].z + whh[r][1].w * thb[b].w;
      // ---- butterfly reduce: even lane l ends with value v=l>>1 ----
      #pragma unroll
      for (int rd = 0; rd < 5; ++rd) {
        const int m = 32 >> rd;
        const int half = 16 >> rd;
        const bool hi = (l & m) != 0;
        #pragma unroll
        for (int j = 0; j < half; ++j) {
          float send = hi ? accH[j] : accH[j + half];
          float recv = __shfl_xor(send, m, 64);
          accH[j] = (hi ? accH[j + half] : accH[j]) + recv;
        }
      }
      accH[0] += __shfl_xor(accH[0], 1, 64);

      // ---- h update + publish th(t+1) ----
      if (redlane) {
        float dh = -hreg + accH[0] + bhh_v + 0.01f * nre;
        hreg += 0.1f * dh;   // ALPHA = DT/TAU
        __hip_atomic_store(
            &th_buf[((((t + 1) & 1) * 16 + g) * 4 + bb) * HHID + grow],
            tanhf(hreg), __ATOMIC_RELAXED, __HIP_MEMORY_SCOPE_AGENT);
      }
      // ---- drain own stores; WG-level arrive; last wave bumps epoch ----
      asm volatile("s_waitcnt vmcnt(0)" ::: "memory");
      if (l == 0) {
        unsigned old = atomicAdd(&s_arrive, 1u);
        if ((old & 3u) == 3u)
          __hip_atomic_fetch_add(&cnt[g * 64], 1u, __ATOMIC_RELAXED,
                                 __HIP_MEMORY_SCOPE_AGENT);
      }
    }

    // ---- Who/out (off the inter-WG critical path) ----
    if (t > 0) {
      float accO[4];
      #pragma unroll
      for (int b = 0; b < 4; ++b)
        accO[b] = who0.x * tha[b].x + who0.y * tha[b].y +
                  who0.z * tha[b].z + who0.w * tha[b].w +
                  who1.x * thb[b].x + who1.y * thb[b].y +
                  who1.z * thb[b].z + who1.w * thb[b].w;
      {
        const bool hi = (l & 32) != 0;
        float s0 = hi ? accO[0] : accO[2];
        float s1 = hi ? accO[1] : accO[3];
        float r0 = __shfl_xor(s0, 32, 64);
        float r1 = __shfl_xor(s1, 32, 64);
        accO[0] = (hi ? accO[2] : accO[0]) + r0;
        accO[1] = (hi ? accO[3] : accO[1]) + r1;
      }
      {
        const bool hi = (l & 16) != 0;
        float s0 = hi ? accO[0] : accO[1];
        float r0 = __shfl_xor(s0, 16, 64);
        accO[0] = (hi ? accO[1] : accO[0]) + r0;
      }
      accO[0] += __shfl_xor(accO[0], 8, 64);
      accO[0] += __shfl_xor(accO[0], 4, 64);
      accO[0] += __shfl_xor(accO[0], 2, 64);
      accO[0] += __shfl_xor(accO[0], 1, 64);
      if (outlane) {
        long oof = (long)OUT_OFF + ((long)(4 * g + ob) * TT + (t - 1)) * OOUT + oc;
        out[oof] = accO[0] + bho_v;
      }
    }
  }

  // ---- final hidden state ----
  if (redlane)
    out[(long)(4 * g + bb) * HHID + grow] = hreg;
}

extern "C" void kernel_launch(void* const* d_in, const int* in_sizes, int n_in,
                              void* d_out, int out_size, void* d_ws, size_t ws_size,
                              hipStream_t stream) {
  const float* inputs  = (const float*)d_in[0];
  const float* hidden  = (const float*)d_in[1];
  const float* innoise = (const float*)d_in[2];
  const float* renoise = (const float*)d_in[3];
  const float* Wih     = (const float*)d_in[4];
  const float* Whh     = (const float*)d_in[5];
  const float* bhh     = (const float*)d_in[6];
  const float* Who     = (const float*)d_in[7];
  const float* bho     = (const float*)d_in[8];
  float* out = (float*)d_out;

  unsigned int* cnt = (unsigned int*)d_ws;              // [16] epochs, 256B stride
  float* th_buf = (float*)((char*)d_ws + 4096);         // [2][16][4][512] f32

  hipMemsetAsync(d_ws, 0, 4096, stream);                // reset epochs

  hipLaunchKernelGGL(rnn_kernel, dim3(256), dim3(NTHR), 0, stream,
                     inputs, hidden, innoise, renoise, Wih, Whh, bhh, Who, bho,
                     out, cnt, th_buf);
}